// Round 1
// baseline (7758.632 us; speedup 1.0000x reference)
//
#include <hip/hip_runtime.h>
#include <math.h>

#define D_DIM  2048
#define BT_DIM 16384   // B*T = 4*4096
#define NSLOTS 4096
#define SCALE  0.02209708691207961f  // 1/sqrt(2048)

// ---------------------------------------------------------------------------
// C[M,N] = alpha * A[M,K] @ B[N,K]^T   (fp32, tiled 128x128, 256 threads)
// Per-K-step local accumulator (16-term partials) keeps fp32 accumulation
// error ~2.7e-7 instead of ~1.6e-6 (serial-2048) -- needed so the top-k
// selection downstream matches the reference.
// ---------------------------------------------------------------------------
__global__ __launch_bounds__(256)
void gemm_abt(const float* __restrict__ A, const float* __restrict__ B,
              float* __restrict__ C, int M, int N, int K, float alpha) {
    __shared__ float As[16][128];   // [k][m]
    __shared__ float Bs[16][128];   // [k][n]

    const int tid = threadIdx.x;
    const int bm  = blockIdx.y * 128;
    const int bn  = blockIdx.x * 128;
    const int ty  = tid >> 4;   // 0..15
    const int tx  = tid & 15;   // 0..15

    float acc[2][2][4][4];
#pragma unroll
    for (int rb = 0; rb < 2; ++rb)
#pragma unroll
        for (int cb = 0; cb < 2; ++cb)
#pragma unroll
            for (int i = 0; i < 4; ++i)
#pragma unroll
                for (int j = 0; j < 4; ++j) acc[rb][cb][i][j] = 0.0f;

    for (int k0 = 0; k0 < K; k0 += 16) {
        // ---- stage 128x16 tiles of A and B into LDS (transposed to [k][m])
#pragma unroll
        for (int half = 0; half < 2; ++half) {
            const int p   = tid + half * 256;   // 0..511 float4 index
            const int row = p >> 2;             // 0..127
            const int kk  = (p & 3) << 2;       // 0,4,8,12
            float4 a4 = *(const float4*)(A + (size_t)(bm + row) * K + (k0 + kk));
            As[kk + 0][row] = a4.x;
            As[kk + 1][row] = a4.y;
            As[kk + 2][row] = a4.z;
            As[kk + 3][row] = a4.w;
            float4 b4 = *(const float4*)(B + (size_t)(bn + row) * K + (k0 + kk));
            Bs[kk + 0][row] = b4.x;
            Bs[kk + 1][row] = b4.y;
            Bs[kk + 2][row] = b4.z;
            Bs[kk + 3][row] = b4.w;
        }
        __syncthreads();

        float lacc[2][2][4][4];
#pragma unroll
        for (int rb = 0; rb < 2; ++rb)
#pragma unroll
            for (int cb = 0; cb < 2; ++cb)
#pragma unroll
                for (int i = 0; i < 4; ++i)
#pragma unroll
                    for (int j = 0; j < 4; ++j) lacc[rb][cb][i][j] = 0.0f;

#pragma unroll
        for (int k = 0; k < 16; ++k) {
            float a[2][4], b[2][4];
#pragma unroll
            for (int h = 0; h < 2; ++h) {
                *(float4*)a[h] = *(const float4*)&As[k][h * 64 + ty * 4];
                *(float4*)b[h] = *(const float4*)&Bs[k][h * 64 + tx * 4];
            }
#pragma unroll
            for (int rb = 0; rb < 2; ++rb)
#pragma unroll
                for (int cb = 0; cb < 2; ++cb)
#pragma unroll
                    for (int i = 0; i < 4; ++i)
#pragma unroll
                        for (int j = 0; j < 4; ++j)
                            lacc[rb][cb][i][j] =
                                fmaf(a[rb][i], b[cb][j], lacc[rb][cb][i][j]);
        }
#pragma unroll
        for (int rb = 0; rb < 2; ++rb)
#pragma unroll
            for (int cb = 0; cb < 2; ++cb)
#pragma unroll
                for (int i = 0; i < 4; ++i)
#pragma unroll
                    for (int j = 0; j < 4; ++j)
                        acc[rb][cb][i][j] += lacc[rb][cb][i][j];
        __syncthreads();
    }

    // ---- store
#pragma unroll
    for (int rb = 0; rb < 2; ++rb)
#pragma unroll
        for (int i = 0; i < 4; ++i) {
            const size_t r = (size_t)(bm + rb * 64 + ty * 4 + i);
#pragma unroll
            for (int cb = 0; cb < 2; ++cb) {
                float4 o;
                o.x = alpha * acc[rb][cb][i][0];
                o.y = alpha * acc[rb][cb][i][1];
                o.z = alpha * acc[rb][cb][i][2];
                o.w = alpha * acc[rb][cb][i][3];
                *(float4*)(C + r * N + (bn + cb * 64 + tx * 4)) = o;
            }
        }
}

// ---------------------------------------------------------------------------
// Per-row top-4 (jax tie semantics: val desc, id asc) + softmax + gather.
// One 256-thread block per row.
// ---------------------------------------------------------------------------
__device__ __forceinline__ bool cand_better(float v, int i, float v2, int i2) {
    return (v > v2) || (v == v2 && i < i2);
}

__device__ __forceinline__ void cand_insert(float v, int idx,
                                            float& v0, int& i0, float& v1, int& i1,
                                            float& v2, int& i2, float& v3, int& i3) {
    if (cand_better(v, idx, v3, i3)) {
        if (cand_better(v, idx, v0, i0)) {
            v3 = v2; i3 = i2; v2 = v1; i2 = i1; v1 = v0; i1 = i0; v0 = v; i0 = idx;
        } else if (cand_better(v, idx, v1, i1)) {
            v3 = v2; i3 = i2; v2 = v1; i2 = i1; v1 = v; i1 = idx;
        } else if (cand_better(v, idx, v2, i2)) {
            v3 = v2; i3 = i2; v2 = v; i2 = idx;
        } else {
            v3 = v; i3 = idx;
        }
    }
}

__global__ __launch_bounds__(256)
void topk_softmax_gather(const float* __restrict__ scores,
                         const float* __restrict__ SV,
                         float* __restrict__ retrieved) {
    const int t = blockIdx.x;
    const float* srow = scores + (size_t)t * NSLOTS;
    const int tid = threadIdx.x;

    float v0 = -INFINITY, v1 = -INFINITY, v2 = -INFINITY, v3 = -INFINITY;
    int   i0 = 0x7fffffff, i1 = 0x7fffffff, i2 = 0x7fffffff, i3 = 0x7fffffff;

#pragma unroll
    for (int j = 0; j < NSLOTS / 256; ++j) {
        const int idx = tid + j * 256;
        const float v = srow[idx];
        cand_insert(v, idx, v0, i0, v1, i1, v2, i2, v3, i3);
    }

    // wave-level butterfly merge (64 lanes)
#pragma unroll
    for (int off = 1; off < 64; off <<= 1) {
        float w0 = __shfl_xor(v0, off), w1 = __shfl_xor(v1, off);
        float w2 = __shfl_xor(v2, off), w3 = __shfl_xor(v3, off);
        int   j0 = __shfl_xor(i0, off), j1 = __shfl_xor(i1, off);
        int   j2 = __shfl_xor(i2, off), j3 = __shfl_xor(i3, off);
        cand_insert(w0, j0, v0, i0, v1, i1, v2, i2, v3, i3);
        cand_insert(w1, j1, v0, i0, v1, i1, v2, i2, v3, i3);
        cand_insert(w2, j2, v0, i0, v1, i1, v2, i2, v3, i3);
        cand_insert(w3, j3, v0, i0, v1, i1, v2, i2, v3, i3);
    }

    __shared__ float lv[4][4];
    __shared__ int   li[4][4];
    __shared__ float swv[4];
    __shared__ int   swi[4];

    const int wave = tid >> 6;
    const int lane = tid & 63;
    if (lane == 0) {
        lv[wave][0] = v0; li[wave][0] = i0;
        lv[wave][1] = v1; li[wave][1] = i1;
        lv[wave][2] = v2; li[wave][2] = i2;
        lv[wave][3] = v3; li[wave][3] = i3;
    }
    __syncthreads();

    if (tid == 0) {
        float m0 = lv[0][0], m1 = lv[0][1], m2 = lv[0][2], m3 = lv[0][3];
        int   n0 = li[0][0], n1 = li[0][1], n2 = li[0][2], n3 = li[0][3];
        for (int w = 1; w < 4; ++w) {
            cand_insert(lv[w][0], li[w][0], m0, n0, m1, n1, m2, n2, m3, n3);
            cand_insert(lv[w][1], li[w][1], m0, n0, m1, n1, m2, n2, m3, n3);
            cand_insert(lv[w][2], li[w][2], m0, n0, m1, n1, m2, n2, m3, n3);
            cand_insert(lv[w][3], li[w][3], m0, n0, m1, n1, m2, n2, m3, n3);
        }
        // softmax over the 4 (max is m0 -- list is sorted)
        const float e0 = 1.0f;
        const float e1 = expf(m1 - m0);
        const float e2 = expf(m2 - m0);
        const float e3 = expf(m3 - m0);
        const float inv = 1.0f / (e0 + e1 + e2 + e3);
        swv[0] = e0 * inv; swi[0] = n0;
        swv[1] = e1 * inv; swi[1] = n1;
        swv[2] = e2 * inv; swi[2] = n2;
        swv[3] = e3 * inv; swi[3] = n3;
    }
    __syncthreads();

    const float w0s = swv[0], w1s = swv[1], w2s = swv[2], w3s = swv[3];
    const int   s0 = swi[0], s1 = swi[1], s2 = swi[2], s3 = swi[3];

    const int d0 = tid * 8;   // 2048 / 256 = 8 floats per thread
    const float4* p0 = (const float4*)(SV + (size_t)s0 * D_DIM + d0);
    const float4* p1 = (const float4*)(SV + (size_t)s1 * D_DIM + d0);
    const float4* p2 = (const float4*)(SV + (size_t)s2 * D_DIM + d0);
    const float4* p3 = (const float4*)(SV + (size_t)s3 * D_DIM + d0);

    float4 r0, r1;
    float4 a0 = p0[0], a1 = p1[0], a2 = p2[0], a3 = p3[0];
    r0.x = w0s * a0.x + w1s * a1.x + w2s * a2.x + w3s * a3.x;
    r0.y = w0s * a0.y + w1s * a1.y + w2s * a2.y + w3s * a3.y;
    r0.z = w0s * a0.z + w1s * a1.z + w2s * a2.z + w3s * a3.z;
    r0.w = w0s * a0.w + w1s * a1.w + w2s * a2.w + w3s * a3.w;
    float4 b0 = p0[1], b1 = p1[1], b2 = p2[1], b3 = p3[1];
    r1.x = w0s * b0.x + w1s * b1.x + w2s * b2.x + w3s * b3.x;
    r1.y = w0s * b0.y + w1s * b1.y + w2s * b2.y + w3s * b3.y;
    r1.z = w0s * b0.z + w1s * b1.z + w2s * b2.z + w3s * b3.z;
    r1.w = w0s * b0.w + w1s * b1.w + w2s * b2.w + w3s * b3.w;

    float* dst = retrieved + (size_t)t * D_DIM + d0;
    *(float4*)(dst + 0) = r0;
    *(float4*)(dst + 4) = r1;
}

// ---------------------------------------------------------------------------
extern "C" void kernel_launch(void* const* d_in, const int* in_sizes, int n_in,
                              void* d_out, int out_size, void* d_ws, size_t ws_size,
                              hipStream_t stream) {
    const float* x    = (const float*)d_in[0];
    const float* sk   = (const float*)d_in[1];
    const float* sv   = (const float*)d_in[2];
    const float* wq   = (const float*)d_in[3];
    const float* wout = (const float*)d_in[4];
    // d_in[5] = top_k (known constant 4)

    float* q      = (float*)d_ws;                       // [BT, D]   134 MB (reused as retrieved)
    float* scores = q + (size_t)BT_DIM * D_DIM;         // [BT, NSLOTS] 268 MB

    const dim3 blk(256);

    // q = x @ Wq^T
    gemm_abt<<<dim3(D_DIM / 128, BT_DIM / 128), blk, 0, stream>>>(
        x, wq, q, BT_DIM, D_DIM, D_DIM, 1.0f);

    // scores = (q @ SK^T) * scale
    gemm_abt<<<dim3(NSLOTS / 128, BT_DIM / 128), blk, 0, stream>>>(
        q, sk, scores, BT_DIM, NSLOTS, D_DIM, SCALE);

    // top-4 + softmax + gather -> retrieved (overwrites q buffer)
    topk_softmax_gather<<<dim3(BT_DIM), blk, 0, stream>>>(scores, sv, q);

    // out = retrieved @ Wout^T
    gemm_abt<<<dim3(D_DIM / 128, BT_DIM / 128), blk, 0, stream>>>(
        q, wout, (float*)d_out, BT_DIM, D_DIM, D_DIM, 1.0f);
}

// Round 2
// 2339.779 us; speedup vs baseline: 3.3160x; 3.3160x over previous
//
#include <hip/hip_runtime.h>
#include <math.h>

#define D_DIM    2048
#define BT_DIM   16384   // B*T
#define NSLOTS   4096
#define SCALE    0.02209708691207961f  // 1/sqrt(2048)
#define MARGIN   0.04f
#define CAND_MAX 32

typedef __attribute__((ext_vector_type(8))) short bf16x8;
typedef __attribute__((ext_vector_type(4))) float f32x4;
typedef __attribute__((ext_vector_type(8))) unsigned short u16x8;

__device__ __forceinline__ unsigned short f2bf(float f) {
    unsigned int u = __float_as_uint(f);
    return (unsigned short)((u + 0x7fffu + ((u >> 16) & 1u)) >> 16);
}

__device__ __forceinline__ void async_cp16(const void* g, void* l) {
    __builtin_amdgcn_global_load_lds(
        (const __attribute__((address_space(1))) void*)g,
        (__attribute__((address_space(3))) void*)l, 16, 0, 0);
}

// ---------------------------------------------------------------------------
// fp32: C[M,N] = A[M,K] @ B[K,N]   (B NOT transposed). Used once for KW=SK@Wq.
// Per-K-step local accumulator for fp32-grade accuracy (feeds exact refine).
// ---------------------------------------------------------------------------
__global__ __launch_bounds__(256)
void gemm_ab_f32(const float* __restrict__ A, const float* __restrict__ B,
                 float* __restrict__ C, int M, int N, int K) {
    __shared__ float As[16][128];   // [k][m]
    __shared__ float Bs[16][128];   // [k][n]

    const int tid = threadIdx.x;
    const int bm  = blockIdx.y * 128;
    const int bn  = blockIdx.x * 128;
    const int ty  = tid >> 4;
    const int tx  = tid & 15;

    float acc[2][2][4][4];
#pragma unroll
    for (int rb = 0; rb < 2; ++rb)
#pragma unroll
        for (int cb = 0; cb < 2; ++cb)
#pragma unroll
            for (int i = 0; i < 4; ++i)
#pragma unroll
                for (int j = 0; j < 4; ++j) acc[rb][cb][i][j] = 0.0f;

    for (int k0 = 0; k0 < K; k0 += 16) {
#pragma unroll
        for (int half = 0; half < 2; ++half) {
            const int p = tid + half * 256;
            const int rowA = p >> 2;
            const int kkA  = (p & 3) << 2;
            float4 a4 = *(const float4*)(A + (size_t)(bm + rowA) * K + (k0 + kkA));
            As[kkA + 0][rowA] = a4.x;
            As[kkA + 1][rowA] = a4.y;
            As[kkA + 2][rowA] = a4.z;
            As[kkA + 3][rowA] = a4.w;
            const int kB = p >> 5;
            const int n4 = (p & 31) << 2;
            float4 b4 = *(const float4*)(B + (size_t)(k0 + kB) * N + (bn + n4));
            *(float4*)&Bs[kB][n4] = b4;
        }
        __syncthreads();

        float lacc[2][2][4][4];
#pragma unroll
        for (int rb = 0; rb < 2; ++rb)
#pragma unroll
            for (int cb = 0; cb < 2; ++cb)
#pragma unroll
                for (int i = 0; i < 4; ++i)
#pragma unroll
                    for (int j = 0; j < 4; ++j) lacc[rb][cb][i][j] = 0.0f;

#pragma unroll
        for (int k = 0; k < 16; ++k) {
            float a[2][4], b[2][4];
#pragma unroll
            for (int h = 0; h < 2; ++h) {
                *(float4*)a[h] = *(const float4*)&As[k][h * 64 + ty * 4];
                *(float4*)b[h] = *(const float4*)&Bs[k][h * 64 + tx * 4];
            }
#pragma unroll
            for (int rb = 0; rb < 2; ++rb)
#pragma unroll
                for (int cb = 0; cb < 2; ++cb)
#pragma unroll
                    for (int i = 0; i < 4; ++i)
#pragma unroll
                        for (int j = 0; j < 4; ++j)
                            lacc[rb][cb][i][j] =
                                fmaf(a[rb][i], b[cb][j], lacc[rb][cb][i][j]);
        }
#pragma unroll
        for (int rb = 0; rb < 2; ++rb)
#pragma unroll
            for (int cb = 0; cb < 2; ++cb)
#pragma unroll
                for (int i = 0; i < 4; ++i)
#pragma unroll
                    for (int j = 0; j < 4; ++j)
                        acc[rb][cb][i][j] += lacc[rb][cb][i][j];
        __syncthreads();
    }

#pragma unroll
    for (int rb = 0; rb < 2; ++rb)
#pragma unroll
        for (int i = 0; i < 4; ++i) {
            const size_t r = (size_t)(bm + rb * 64 + ty * 4 + i);
#pragma unroll
            for (int cb = 0; cb < 2; ++cb) {
                float4 o;
                o.x = acc[rb][cb][i][0];
                o.y = acc[rb][cb][i][1];
                o.z = acc[rb][cb][i][2];
                o.w = acc[rb][cb][i][3];
                *(float4*)(C + r * N + (bn + cb * 64 + tx * 4)) = o;
            }
        }
}

// ---------------------------------------------------------------------------
// fp32 -> bf16 elementwise (8 elems/thread), exact grid
// ---------------------------------------------------------------------------
__global__ __launch_bounds__(256)
void cvt_f32_bf16(const float* __restrict__ in, unsigned short* __restrict__ out) {
    const size_t i = ((size_t)blockIdx.x * 256 + threadIdx.x) * 8;
    float4 a = *(const float4*)(in + i);
    float4 b = *(const float4*)(in + i + 4);
    u16x8 o;
    o[0] = f2bf(a.x); o[1] = f2bf(a.y); o[2] = f2bf(a.z); o[3] = f2bf(a.w);
    o[4] = f2bf(b.x); o[5] = f2bf(b.y); o[6] = f2bf(b.z); o[7] = f2bf(b.w);
    *(u16x8*)(out + i) = o;
}

// ---------------------------------------------------------------------------
// bf16 MFMA GEMM: C[M,N] = A[M,K] @ B[N,K]^T, fp32 out.
// 128x128 tile, BK=32, 4 waves (2x2), 16x16x32 MFMA, global_load_lds w=16.
// LDS tiles [128 rows][32 k] bf16 (64 B rows). XOR swizzle: physical k-slot
// kslot holds logical chunk kslot ^ ((row>>1)&3); applied via pre-swizzled
// GLOBAL source (linear LDS dest, rule: both-sides-or-neither).
// ---------------------------------------------------------------------------
__global__ __launch_bounds__(256)
void gemm_bf16_abt(const unsigned short* __restrict__ A,
                   const unsigned short* __restrict__ B,
                   float* __restrict__ C, int M, int N, int K) {
    __shared__ __align__(16) unsigned short Alds[128 * 32];
    __shared__ __align__(16) unsigned short Blds[128 * 32];

    const int tid  = threadIdx.x;
    const int lane = tid & 63;
    const int w    = tid >> 6;
    const int wr   = w >> 1, wc = w & 1;
    const int bm   = blockIdx.y * 128;
    const int bn   = blockIdx.x * 128;

    // --- staging constants: wave w covers chunks {w, w+4} (16 rows each)
    const int srow = lane >> 2;                       // row within chunk
    const int skch = (lane & 3) ^ ((lane >> 3) & 3);  // logical k-chunk for this lane's slot
    const int c0 = w, c1 = w + 4;
    const unsigned short* gA0 = A + (size_t)(bm + c0 * 16 + srow) * K + skch * 8;
    const unsigned short* gA1 = A + (size_t)(bm + c1 * 16 + srow) * K + skch * 8;
    const unsigned short* gB0 = B + (size_t)(bn + c0 * 16 + srow) * K + skch * 8;
    const unsigned short* gB1 = B + (size_t)(bn + c1 * 16 + srow) * K + skch * 8;
    char* lA0 = (char*)Alds + c0 * 1024;
    char* lA1 = (char*)Alds + c1 * 1024;
    char* lB0 = (char*)Blds + c0 * 1024;
    char* lB1 = (char*)Blds + c1 * 1024;

    // --- read constants: swizzled k-offset is per-lane constant
    const int kbyte = (((lane >> 4) ^ ((lane >> 1) & 3)) << 4);
    const int rA = wr * 64 + (lane & 15);
    const int rB = wc * 64 + (lane & 15);

    f32x4 acc[4][4] = {};

    for (int kt = 0; kt < K; kt += 32) {
        async_cp16(gA0, lA0);
        async_cp16(gA1, lA1);
        async_cp16(gB0, lB0);
        async_cp16(gB1, lB1);
        gA0 += 32; gA1 += 32; gB0 += 32; gB1 += 32;
        __syncthreads();   // drains vmcnt before barrier

        bf16x8 a[4], b[4];
#pragma unroll
        for (int i = 0; i < 4; ++i) {
            a[i] = *(const bf16x8*)((const char*)Alds + (rA + i * 16) * 64 + kbyte);
            b[i] = *(const bf16x8*)((const char*)Blds + (rB + i * 16) * 64 + kbyte);
        }
#pragma unroll
        for (int i = 0; i < 4; ++i)
#pragma unroll
            for (int j = 0; j < 4; ++j)
                acc[i][j] = __builtin_amdgcn_mfma_f32_16x16x32_bf16(
                    a[i], b[j], acc[i][j], 0, 0, 0);
        __syncthreads();
    }

    // C/D layout: col = lane&15, row = (lane>>4)*4 + reg   [m89/m91 verified]
    const int orow = (lane >> 4) * 4;
    const int ocol = lane & 15;
#pragma unroll
    for (int i = 0; i < 4; ++i)
#pragma unroll
        for (int j = 0; j < 4; ++j) {
            const size_t base =
                (size_t)(bm + wr * 64 + i * 16 + orow) * N + (bn + wc * 64 + j * 16 + ocol);
#pragma unroll
            for (int r = 0; r < 4; ++r)
                C[base + (size_t)r * N] = acc[i][j][r];
        }
}

// ---------------------------------------------------------------------------
// top-4 helpers (jax semantics: val desc, idx asc)
// ---------------------------------------------------------------------------
__device__ __forceinline__ bool cand_better(float v, int i, float v2, int i2) {
    return (v > v2) || (v == v2 && i < i2);
}

__device__ __forceinline__ void cand_insert(float v, int idx,
                                            float& v0, int& i0, float& v1, int& i1,
                                            float& v2, int& i2, float& v3, int& i3) {
    if (cand_better(v, idx, v3, i3)) {
        if (cand_better(v, idx, v0, i0)) {
            v3 = v2; i3 = i2; v2 = v1; i2 = i1; v1 = v0; i1 = i0; v0 = v; i0 = idx;
        } else if (cand_better(v, idx, v1, i1)) {
            v3 = v2; i3 = i2; v2 = v1; i2 = i1; v1 = v; i1 = idx;
        } else if (cand_better(v, idx, v2, i2)) {
            v3 = v2; i3 = i2; v2 = v; i2 = idx;
        } else {
            v3 = v; i3 = idx;
        }
    }
}

// ---------------------------------------------------------------------------
// Per-row: approx top-4 -> margin-collect candidates -> EXACT fp32 re-score
// -> top-4 + softmax(scale) -> gather SV -> write retrieved (bf16).
// One 256-thread block per row.
// ---------------------------------------------------------------------------
__global__ __launch_bounds__(256)
void topk_refine(const float* __restrict__ scores, const float* __restrict__ x,
                 const float* __restrict__ KW, const float* __restrict__ SV,
                 unsigned short* __restrict__ retr) {
    const int t    = blockIdx.x;
    const int tid  = threadIdx.x;
    const int lane = tid & 63;
    const int wave = tid >> 6;
    const float* srow = scores + (size_t)t * NSLOTS;

    float sc[16];
#pragma unroll
    for (int j = 0; j < 16; ++j) sc[j] = srow[tid + j * 256];

    // --- approximate top-4 (thread-local -> wave butterfly -> cross-wave)
    float v0 = -INFINITY, v1 = -INFINITY, v2 = -INFINITY, v3 = -INFINITY;
    int   i0 = 0x7fffffff, i1 = 0x7fffffff, i2 = 0x7fffffff, i3 = 0x7fffffff;
#pragma unroll
    for (int j = 0; j < 16; ++j)
        cand_insert(sc[j], tid + j * 256, v0, i0, v1, i1, v2, i2, v3, i3);

#pragma unroll
    for (int off = 1; off < 64; off <<= 1) {
        float w0 = __shfl_xor(v0, off), w1 = __shfl_xor(v1, off);
        float w2 = __shfl_xor(v2, off), w3 = __shfl_xor(v3, off);
        int   j0 = __shfl_xor(i0, off), j1 = __shfl_xor(i1, off);
        int   j2 = __shfl_xor(i2, off), j3 = __shfl_xor(i3, off);
        cand_insert(w0, j0, v0, i0, v1, i1, v2, i2, v3, i3);
        cand_insert(w1, j1, v0, i0, v1, i1, v2, i2, v3, i3);
        cand_insert(w2, j2, v0, i0, v1, i1, v2, i2, v3, i3);
        cand_insert(w3, j3, v0, i0, v1, i1, v2, i2, v3, i3);
    }

    __shared__ float lv[4][4];
    __shared__ int   li[4][4];
    if (lane == 0) {
        lv[wave][0] = v0; li[wave][0] = i0;
        lv[wave][1] = v1; li[wave][1] = i1;
        lv[wave][2] = v2; li[wave][2] = i2;
        lv[wave][3] = v3; li[wave][3] = i3;
    }
    __syncthreads();

    float m0 = -INFINITY, m1 = -INFINITY, m2 = -INFINITY, m3 = -INFINITY;
    int   n0 = 0x7fffffff, n1 = 0x7fffffff, n2 = 0x7fffffff, n3 = 0x7fffffff;
#pragma unroll
    for (int ww = 0; ww < 4; ++ww)
#pragma unroll
        for (int q = 0; q < 4; ++q)
            cand_insert(lv[ww][q], li[ww][q], m0, n0, m1, n1, m2, n2, m3, n3);

    const float thresh = m3 - MARGIN;

    // --- collect candidates within margin of approx 4th
    __shared__ int   cand[CAND_MAX];
    __shared__ int   ncand;
    __shared__ float wsum[4];
    if (tid == 0) ncand = 0;
    __syncthreads();
#pragma unroll
    for (int j = 0; j < 16; ++j)
        if (sc[j] >= thresh) {
            int p = atomicAdd(&ncand, 1);
            if (p < CAND_MAX) cand[p] = tid + j * 256;
        }
    __syncthreads();
    const int nc = min(ncand, CAND_MAX);

    // --- exact fp32 re-score of candidates (block tree-reduce, deterministic)
    const float* xrow = x + (size_t)t * D_DIM + tid * 8;
    const float4 xa = *(const float4*)xrow;
    const float4 xc = *(const float4*)(xrow + 4);

    float r0 = -INFINITY, r1 = -INFINITY, r2 = -INFINITY, r3 = -INFINITY;
    int   q0 = 0x7fffffff, q1 = 0x7fffffff, q2 = 0x7fffffff, q3 = 0x7fffffff;
    for (int c = 0; c < nc; ++c) {
        const int slot = cand[c];
        const float* kr = KW + (size_t)slot * D_DIM + tid * 8;
        const float4 ka = *(const float4*)kr;
        const float4 kc = *(const float4*)(kr + 4);
        float p = xa.x * ka.x;
        p = fmaf(xa.y, ka.y, p); p = fmaf(xa.z, ka.z, p); p = fmaf(xa.w, ka.w, p);
        p = fmaf(xc.x, kc.x, p); p = fmaf(xc.y, kc.y, p);
        p = fmaf(xc.z, kc.z, p); p = fmaf(xc.w, kc.w, p);
#pragma unroll
        for (int off = 32; off >= 1; off >>= 1) p += __shfl_xor(p, off);
        if (lane == 0) wsum[wave] = p;
        __syncthreads();
        const float s = (wsum[0] + wsum[1]) + (wsum[2] + wsum[3]);
        cand_insert(s, slot, r0, q0, r1, q1, r2, q2, r3, q3);
        __syncthreads();
    }

    // --- softmax over scaled top-4 (r0 is max)
    const float e1 = expf(SCALE * (r1 - r0));
    const float e2 = expf(SCALE * (r2 - r0));
    const float e3 = expf(SCALE * (r3 - r0));
    const float inv = 1.0f / (1.0f + e1 + e2 + e3);
    const float w0s = inv, w1s = e1 * inv, w2s = e2 * inv, w3s = e3 * inv;

    // --- gather + weighted sum -> bf16
    const int d0 = tid * 8;
    const float* p0 = SV + (size_t)q0 * D_DIM + d0;
    const float* p1 = SV + (size_t)q1 * D_DIM + d0;
    const float* p2 = SV + (size_t)q2 * D_DIM + d0;
    const float* p3 = SV + (size_t)q3 * D_DIM + d0;

    float4 a0 = *(const float4*)p0, a1 = *(const float4*)p1;
    float4 a2 = *(const float4*)p2, a3 = *(const float4*)p3;
    float4 b0 = *(const float4*)(p0 + 4), b1 = *(const float4*)(p1 + 4);
    float4 b2 = *(const float4*)(p2 + 4), b3 = *(const float4*)(p3 + 4);

    u16x8 o;
    o[0] = f2bf(w0s * a0.x + w1s * a1.x + w2s * a2.x + w3s * a3.x);
    o[1] = f2bf(w0s * a0.y + w1s * a1.y + w2s * a2.y + w3s * a3.y);
    o[2] = f2bf(w0s * a0.z + w1s * a1.z + w2s * a2.z + w3s * a3.z);
    o[3] = f2bf(w0s * a0.w + w1s * a1.w + w2s * a2.w + w3s * a3.w);
    o[4] = f2bf(w0s * b0.x + w1s * b1.x + w2s * b2.x + w3s * b3.x);
    o[5] = f2bf(w0s * b0.y + w1s * b1.y + w2s * b2.y + w3s * b3.y);
    o[6] = f2bf(w0s * b0.z + w1s * b1.z + w2s * b2.z + w3s * b3.z);
    o[7] = f2bf(w0s * b0.w + w1s * b1.w + w2s * b2.w + w3s * b3.w);
    *(u16x8*)(retr + (size_t)t * D_DIM + d0) = o;
}

// ---------------------------------------------------------------------------
extern "C" void kernel_launch(void* const* d_in, const int* in_sizes, int n_in,
                              void* d_out, int out_size, void* d_ws, size_t ws_size,
                              hipStream_t stream) {
    const float* x    = (const float*)d_in[0];
    const float* sk   = (const float*)d_in[1];
    const float* sv   = (const float*)d_in[2];
    const float* wq   = (const float*)d_in[3];
    const float* wout = (const float*)d_in[4];

    // workspace layout (394.3 MB total; round-1 proved ws >= 402.6 MB)
    float*          scores = (float*)d_ws;                                   // 268.4 MB
    float*          KW     = scores + (size_t)BT_DIM * NSLOTS;               //  33.6 MB
    unsigned short* woutb  = (unsigned short*)(KW + (size_t)NSLOTS * D_DIM); //   8.4 MB
    unsigned short* kwb    = woutb + (size_t)D_DIM * D_DIM;                  //  16.8 MB
    unsigned short* xb     = kwb + (size_t)NSLOTS * D_DIM;                   //  67.1 MB (reused as retr)

    const dim3 blk(256);

    // KW = SK @ Wq   (fp32-exact; feeds refinement)
    gemm_ab_f32<<<dim3(D_DIM / 128, NSLOTS / 128), blk, 0, stream>>>(
        sk, wq, KW, NSLOTS, D_DIM, D_DIM);

    // bf16 copies
    cvt_f32_bf16<<<dim3((BT_DIM * (size_t)D_DIM) / 2048), blk, 0, stream>>>(x, xb);
    cvt_f32_bf16<<<dim3((NSLOTS * (size_t)D_DIM) / 2048), blk, 0, stream>>>(KW, kwb);
    cvt_f32_bf16<<<dim3((D_DIM * (size_t)D_DIM) / 2048), blk, 0, stream>>>(wout, woutb);

    // approx scores = xb @ kwb^T  (unscaled)
    gemm_bf16_abt<<<dim3(NSLOTS / 128, BT_DIM / 128), blk, 0, stream>>>(
        xb, kwb, scores, BT_DIM, NSLOTS, D_DIM);

    // exact top-4 via margin-refine; writes retrieved (bf16) over xb
    topk_refine<<<dim3(BT_DIM), blk, 0, stream>>>(scores, x, KW, sv, xb);

    // out = retrieved @ Wout^T
    gemm_bf16_abt<<<dim3(D_DIM / 128, BT_DIM / 128), blk, 0, stream>>>(
        xb, woutb, (float*)d_out, BT_DIM, D_DIM, D_DIM);
}

// Round 3
// 1746.262 us; speedup vs baseline: 4.4430x; 1.3399x over previous
//
#include <hip/hip_runtime.h>
#include <math.h>

#define D_DIM    2048
#define BT_DIM   16384   // B*T
#define NSLOTS   4096
#define SCALE    0.02209708691207961f  // 1/sqrt(2048)
#define MARGIN   0.02f
#define CAND_MAX 16
#define KSPLIT   4

typedef __attribute__((ext_vector_type(8))) short bf16x8;
typedef __attribute__((ext_vector_type(4))) float f32x4;
typedef __attribute__((ext_vector_type(8))) unsigned short u16x8;
typedef __attribute__((ext_vector_type(4))) unsigned short u16x4;

__device__ __forceinline__ unsigned short f2bf(float f) {
    unsigned int u = __float_as_uint(f);
    return (unsigned short)((u + 0x7fffu + ((u >> 16) & 1u)) >> 16);
}
__device__ __forceinline__ float bf2f(unsigned short s) {
    return __uint_as_float(((unsigned int)s) << 16);
}

__device__ __forceinline__ void async_cp16(const void* g, void* l) {
    __builtin_amdgcn_global_load_lds(
        (const __attribute__((address_space(1))) void*)g,
        (__attribute__((address_space(3))) void*)l, 16, 0, 0);
}

// ---------------------------------------------------------------------------
// fp32: Cpart[z] = A[M,Kc] @ B[Kc,N] for K-chunk z (K-split for occupancy).
// Per-K-step local accumulator for fp32-grade accuracy (feeds exact refine).
// ---------------------------------------------------------------------------
__global__ __launch_bounds__(256)
void gemm_ab_f32_ksplit(const float* __restrict__ A, const float* __restrict__ B,
                        float* __restrict__ Cpart, int M, int N, int K) {
    __shared__ float As[16][128];   // [k][m]
    __shared__ float Bs[16][128];   // [k][n]

    const int tid = threadIdx.x;
    const int bm  = blockIdx.y * 128;
    const int bn  = blockIdx.x * 128;
    const int kc  = K / KSPLIT;
    const int ks  = blockIdx.z * kc;
    float* C = Cpart + (size_t)blockIdx.z * M * N;
    const int ty  = tid >> 4;
    const int tx  = tid & 15;

    float acc[2][2][4][4];
#pragma unroll
    for (int rb = 0; rb < 2; ++rb)
#pragma unroll
        for (int cb = 0; cb < 2; ++cb)
#pragma unroll
            for (int i = 0; i < 4; ++i)
#pragma unroll
                for (int j = 0; j < 4; ++j) acc[rb][cb][i][j] = 0.0f;

    for (int k0 = ks; k0 < ks + kc; k0 += 16) {
#pragma unroll
        for (int half = 0; half < 2; ++half) {
            const int p = tid + half * 256;
            const int rowA = p >> 2;
            const int kkA  = (p & 3) << 2;
            float4 a4 = *(const float4*)(A + (size_t)(bm + rowA) * K + (k0 + kkA));
            As[kkA + 0][rowA] = a4.x;
            As[kkA + 1][rowA] = a4.y;
            As[kkA + 2][rowA] = a4.z;
            As[kkA + 3][rowA] = a4.w;
            const int kB = p >> 5;
            const int n4 = (p & 31) << 2;
            float4 b4 = *(const float4*)(B + (size_t)(k0 + kB) * N + (bn + n4));
            *(float4*)&Bs[kB][n4] = b4;
        }
        __syncthreads();

        float lacc[2][2][4][4];
#pragma unroll
        for (int rb = 0; rb < 2; ++rb)
#pragma unroll
            for (int cb = 0; cb < 2; ++cb)
#pragma unroll
                for (int i = 0; i < 4; ++i)
#pragma unroll
                    for (int j = 0; j < 4; ++j) lacc[rb][cb][i][j] = 0.0f;

#pragma unroll
        for (int k = 0; k < 16; ++k) {
            float a[2][4], b[2][4];
#pragma unroll
            for (int h = 0; h < 2; ++h) {
                *(float4*)a[h] = *(const float4*)&As[k][h * 64 + ty * 4];
                *(float4*)b[h] = *(const float4*)&Bs[k][h * 64 + tx * 4];
            }
#pragma unroll
            for (int rb = 0; rb < 2; ++rb)
#pragma unroll
                for (int cb = 0; cb < 2; ++cb)
#pragma unroll
                    for (int i = 0; i < 4; ++i)
#pragma unroll
                        for (int j = 0; j < 4; ++j)
                            lacc[rb][cb][i][j] =
                                fmaf(a[rb][i], b[cb][j], lacc[rb][cb][i][j]);
        }
#pragma unroll
        for (int rb = 0; rb < 2; ++rb)
#pragma unroll
            for (int cb = 0; cb < 2; ++cb)
#pragma unroll
                for (int i = 0; i < 4; ++i)
#pragma unroll
                    for (int j = 0; j < 4; ++j)
                        acc[rb][cb][i][j] += lacc[rb][cb][i][j];
        __syncthreads();
    }

#pragma unroll
    for (int rb = 0; rb < 2; ++rb)
#pragma unroll
        for (int i = 0; i < 4; ++i) {
            const size_t r = (size_t)(bm + rb * 64 + ty * 4 + i);
#pragma unroll
            for (int cb = 0; cb < 2; ++cb) {
                float4 o;
                o.x = acc[rb][cb][i][0];
                o.y = acc[rb][cb][i][1];
                o.z = acc[rb][cb][i][2];
                o.w = acc[rb][cb][i][3];
                *(float4*)(C + r * N + (bn + cb * 64 + tx * 4)) = o;
            }
        }
}

// ---------------------------------------------------------------------------
// KW = sum of 4 K-chunk partials (deterministic); also emit kwb = bf16(KW).
// 4 floats per thread.
// ---------------------------------------------------------------------------
__global__ __launch_bounds__(256)
void reduce_kw(const float* __restrict__ part, float* __restrict__ KW,
               unsigned short* __restrict__ kwb) {
    const size_t i = ((size_t)blockIdx.x * 256 + threadIdx.x) * 4;
    const size_t stride = (size_t)NSLOTS * D_DIM;
    float4 s0 = *(const float4*)(part + i);
    float4 s1 = *(const float4*)(part + i + stride);
    float4 s2 = *(const float4*)(part + i + 2 * stride);
    float4 s3 = *(const float4*)(part + i + 3 * stride);
    float4 o;
    o.x = (s0.x + s1.x) + (s2.x + s3.x);
    o.y = (s0.y + s1.y) + (s2.y + s3.y);
    o.z = (s0.z + s1.z) + (s2.z + s3.z);
    o.w = (s0.w + s1.w) + (s2.w + s3.w);
    *(float4*)(KW + i) = o;
    u16x4 b;
    b[0] = f2bf(o.x); b[1] = f2bf(o.y); b[2] = f2bf(o.z); b[3] = f2bf(o.w);
    *(u16x4*)(kwb + i) = b;
}

// ---------------------------------------------------------------------------
// fp32 -> bf16 elementwise (8 elems/thread), exact grid
// ---------------------------------------------------------------------------
__global__ __launch_bounds__(256)
void cvt_f32_bf16(const float* __restrict__ in, unsigned short* __restrict__ out) {
    const size_t i = ((size_t)blockIdx.x * 256 + threadIdx.x) * 8;
    float4 a = *(const float4*)(in + i);
    float4 b = *(const float4*)(in + i + 4);
    u16x8 o;
    o[0] = f2bf(a.x); o[1] = f2bf(a.y); o[2] = f2bf(a.z); o[3] = f2bf(a.w);
    o[4] = f2bf(b.x); o[5] = f2bf(b.y); o[6] = f2bf(b.z); o[7] = f2bf(b.w);
    *(u16x8*)(out + i) = o;
}

// ---------------------------------------------------------------------------
// bf16 MFMA GEMM: C[M,N] = A[M,K] @ B[N,K]^T; C is fp32 or bf16 (template).
// 128x128 tile, BK=32, 4 waves, 16x16x32 MFMA, global_load_lds w=16,
// XOR-swizzled via pre-swizzled global source (linear LDS dest).
// ---------------------------------------------------------------------------
template <bool BF16_OUT>
__global__ __launch_bounds__(256)
void gemm_bf16_abt(const unsigned short* __restrict__ A,
                   const unsigned short* __restrict__ B,
                   void* __restrict__ Cv, int M, int N, int K) {
    __shared__ __align__(16) unsigned short Alds[128 * 32];
    __shared__ __align__(16) unsigned short Blds[128 * 32];

    const int tid  = threadIdx.x;
    const int lane = tid & 63;
    const int w    = tid >> 6;
    const int wr   = w >> 1, wc = w & 1;
    const int bm   = blockIdx.y * 128;
    const int bn   = blockIdx.x * 128;

    const int srow = lane >> 2;
    const int skch = (lane & 3) ^ ((lane >> 3) & 3);
    const int c0 = w, c1 = w + 4;
    const unsigned short* gA0 = A + (size_t)(bm + c0 * 16 + srow) * K + skch * 8;
    const unsigned short* gA1 = A + (size_t)(bm + c1 * 16 + srow) * K + skch * 8;
    const unsigned short* gB0 = B + (size_t)(bn + c0 * 16 + srow) * K + skch * 8;
    const unsigned short* gB1 = B + (size_t)(bn + c1 * 16 + srow) * K + skch * 8;
    char* lA0 = (char*)Alds + c0 * 1024;
    char* lA1 = (char*)Alds + c1 * 1024;
    char* lB0 = (char*)Blds + c0 * 1024;
    char* lB1 = (char*)Blds + c1 * 1024;

    const int kbyte = (((lane >> 4) ^ ((lane >> 1) & 3)) << 4);
    const int rA = wr * 64 + (lane & 15);
    const int rB = wc * 64 + (lane & 15);

    f32x4 acc[4][4] = {};

    for (int kt = 0; kt < K; kt += 32) {
        async_cp16(gA0, lA0);
        async_cp16(gA1, lA1);
        async_cp16(gB0, lB0);
        async_cp16(gB1, lB1);
        gA0 += 32; gA1 += 32; gB0 += 32; gB1 += 32;
        __syncthreads();

        bf16x8 a[4], b[4];
#pragma unroll
        for (int i = 0; i < 4; ++i) {
            a[i] = *(const bf16x8*)((const char*)Alds + (rA + i * 16) * 64 + kbyte);
            b[i] = *(const bf16x8*)((const char*)Blds + (rB + i * 16) * 64 + kbyte);
        }
#pragma unroll
        for (int i = 0; i < 4; ++i)
#pragma unroll
            for (int j = 0; j < 4; ++j)
                acc[i][j] = __builtin_amdgcn_mfma_f32_16x16x32_bf16(
                    a[i], b[j], acc[i][j], 0, 0, 0);
        __syncthreads();
    }

    const int orow = (lane >> 4) * 4;
    const int ocol = lane & 15;
#pragma unroll
    for (int i = 0; i < 4; ++i)
#pragma unroll
        for (int j = 0; j < 4; ++j) {
            const size_t base =
                (size_t)(bm + wr * 64 + i * 16 + orow) * N + (bn + wc * 64 + j * 16 + ocol);
#pragma unroll
            for (int r = 0; r < 4; ++r) {
                if constexpr (BF16_OUT)
                    ((unsigned short*)Cv)[base + (size_t)r * N] = f2bf(acc[i][j][r]);
                else
                    ((float*)Cv)[base + (size_t)r * N] = acc[i][j][r];
            }
        }
}

// ---------------------------------------------------------------------------
// top-4 helpers (jax semantics: val desc, idx asc)
// ---------------------------------------------------------------------------
__device__ __forceinline__ bool cand_better(float v, int i, float v2, int i2) {
    return (v > v2) || (v == v2 && i < i2);
}

__device__ __forceinline__ void cand_insert(float v, int idx,
                                            float& v0, int& i0, float& v1, int& i1,
                                            float& v2, int& i2, float& v3, int& i3) {
    if (cand_better(v, idx, v3, i3)) {
        if (cand_better(v, idx, v0, i0)) {
            v3 = v2; i3 = i2; v2 = v1; i2 = i1; v1 = v0; i1 = i0; v0 = v; i0 = idx;
        } else if (cand_better(v, idx, v1, i1)) {
            v3 = v2; i3 = i2; v2 = v1; i2 = i1; v1 = v; i1 = idx;
        } else if (cand_better(v, idx, v2, i2)) {
            v3 = v2; i3 = i2; v2 = v; i2 = idx;
        } else {
            v3 = v; i3 = idx;
        }
    }
}

// ---------------------------------------------------------------------------
// Wave-per-row: approx top-4 (bf16 scores) -> margin-collect -> exact fp32
// re-score (wave-local, no block syncs in loop) -> softmax -> bf16 gather
// -> retr. 4 rows per 256-thread block.
// ---------------------------------------------------------------------------
__global__ __launch_bounds__(256)
void topk_refine(const unsigned short* __restrict__ scoresb,
                 const float* __restrict__ x,
                 const float* __restrict__ KW,
                 const unsigned short* __restrict__ svb,
                 unsigned short* __restrict__ retr) {
    const int tid  = threadIdx.x;
    const int lane = tid & 63;
    const int w    = tid >> 6;
    const int t    = blockIdx.x * 4 + w;
    const unsigned short* srow = scoresb + (size_t)t * NSLOTS;

    __shared__ int cand[4][CAND_MAX];
    __shared__ int ncand[4];
    if (lane == 0) ncand[w] = 0;
    __syncthreads();

    // --- phase 1: approx top-4 over the row (64 bf16 values per lane)
    float v0 = -INFINITY, v1 = -INFINITY, v2 = -INFINITY, v3 = -INFINITY;
    int   i0 = 0x7fffffff, i1 = 0x7fffffff, i2 = 0x7fffffff, i3 = 0x7fffffff;
#pragma unroll
    for (int j = 0; j < 8; ++j) {
        u16x8 s8 = *(const u16x8*)(srow + lane * 8 + 512 * j);
#pragma unroll
        for (int e = 0; e < 8; ++e) {
            const float v = bf2f(s8[e]);
            cand_insert(v, lane * 8 + 512 * j + e, v0, i0, v1, i1, v2, i2, v3, i3);
        }
    }
    // wave butterfly -> all lanes hold global approx top-4
#pragma unroll
    for (int off = 1; off < 64; off <<= 1) {
        float w0 = __shfl_xor(v0, off), w1 = __shfl_xor(v1, off);
        float w2 = __shfl_xor(v2, off), w3 = __shfl_xor(v3, off);
        int   j0 = __shfl_xor(i0, off), j1 = __shfl_xor(i1, off);
        int   j2 = __shfl_xor(i2, off), j3 = __shfl_xor(i3, off);
        cand_insert(w0, j0, v0, i0, v1, i1, v2, i2, v3, i3);
        cand_insert(w1, j1, v0, i0, v1, i1, v2, i2, v3, i3);
        cand_insert(w2, j2, v0, i0, v1, i1, v2, i2, v3, i3);
        cand_insert(w3, j3, v0, i0, v1, i1, v2, i2, v3, i3);
    }
    const float thresh = v3 - MARGIN;

    // --- phase 2: margin-collect candidate slots (re-read, L1/L2-hot)
#pragma unroll
    for (int j = 0; j < 8; ++j) {
        u16x8 s8 = *(const u16x8*)(srow + lane * 8 + 512 * j);
#pragma unroll
        for (int e = 0; e < 8; ++e) {
            if (bf2f(s8[e]) >= thresh) {
                int p = atomicAdd(&ncand[w], 1);
                if (p < CAND_MAX) cand[w][p] = lane * 8 + 512 * j + e;
            }
        }
    }
    __syncthreads();
    const int nc = min(ncand[w], CAND_MAX);

    // --- phase 3: x row into registers (32 floats per lane)
    const float* xrow = x + (size_t)t * D_DIM + lane * 4;
    float4 xv[8];
#pragma unroll
    for (int i = 0; i < 8; ++i) xv[i] = *(const float4*)(xrow + 256 * i);

    // --- phase 4: exact fp32 re-score, wave-local
    float r0 = -INFINITY, r1 = -INFINITY, r2 = -INFINITY, r3 = -INFINITY;
    int   q0 = 0x7fffffff, q1 = 0x7fffffff, q2 = 0x7fffffff, q3 = 0x7fffffff;
    for (int c = 0; c < nc; ++c) {
        const int slot = cand[w][c];
        const float* kr = KW + (size_t)slot * D_DIM + lane * 4;
        float p = 0.0f;
#pragma unroll
        for (int i = 0; i < 8; ++i) {
            const float4 k4 = *(const float4*)(kr + 256 * i);
            p = fmaf(xv[i].x, k4.x, p);
            p = fmaf(xv[i].y, k4.y, p);
            p = fmaf(xv[i].z, k4.z, p);
            p = fmaf(xv[i].w, k4.w, p);
        }
#pragma unroll
        for (int off = 1; off < 64; off <<= 1) p += __shfl_xor(p, off);
        cand_insert(p, slot, r0, q0, r1, q1, r2, q2, r3, q3);
    }

    // --- phase 5: softmax over scaled top-4 (r0 is max)
    const float e1 = expf(SCALE * (r1 - r0));
    const float e2 = expf(SCALE * (r2 - r0));
    const float e3 = expf(SCALE * (r3 - r0));
    const float inv = 1.0f / (1.0f + e1 + e2 + e3);
    const float w0s = inv, w1s = e1 * inv, w2s = e2 * inv, w3s = e3 * inv;

    // --- phase 6: gather bf16 SV rows, weighted sum, write retr (bf16)
    const unsigned short* p0 = svb + (size_t)q0 * D_DIM;
    const unsigned short* p1 = svb + (size_t)q1 * D_DIM;
    const unsigned short* p2 = svb + (size_t)q2 * D_DIM;
    const unsigned short* p3 = svb + (size_t)q3 * D_DIM;
    unsigned short* orow = retr + (size_t)t * D_DIM;
#pragma unroll
    for (int i = 0; i < 4; ++i) {
        const int d0 = lane * 8 + 512 * i;
        u16x8 a0 = *(const u16x8*)(p0 + d0);
        u16x8 a1 = *(const u16x8*)(p1 + d0);
        u16x8 a2 = *(const u16x8*)(p2 + d0);
        u16x8 a3 = *(const u16x8*)(p3 + d0);
        u16x8 o;
#pragma unroll
        for (int e = 0; e < 8; ++e) {
            float s = w0s * bf2f(a0[e]) + w1s * bf2f(a1[e]) +
                      w2s * bf2f(a2[e]) + w3s * bf2f(a3[e]);
            o[e] = f2bf(s);
        }
        *(u16x8*)(orow + d0) = o;
    }
}

// ---------------------------------------------------------------------------
extern "C" void kernel_launch(void* const* d_in, const int* in_sizes, int n_in,
                              void* d_out, int out_size, void* d_ws, size_t ws_size,
                              hipStream_t stream) {
    const float* x    = (const float*)d_in[0];
    const float* sk   = (const float*)d_in[1];
    const float* sv   = (const float*)d_in[2];
    const float* wq   = (const float*)d_in[3];
    const float* wout = (const float*)d_in[4];

    // workspace layout (276.9 MB; proven ws >= 402 MB)
    char* base = (char*)d_ws;
    // region A (134.2 MB): KW partials first, then reused as bf16 scores
    float*          kwpart  = (float*)base;                       // 4 x 33.55 MB
    unsigned short* scoresb = (unsigned short*)base;              // 134.2 MB (after reduce)
    float*          KW      = (float*)(base + 134217728);         //  33.55 MB
    unsigned short* kwb     = (unsigned short*)(base + 167772160);//  16.78 MB
    unsigned short* woutb   = (unsigned short*)(base + 184549376);//   8.39 MB
    unsigned short* xb      = (unsigned short*)(base + 192937984);//  67.11 MB (reused as retr)
    unsigned short* svb     = (unsigned short*)(base + 260046848);//  16.78 MB

    const dim3 blk(256);

    // KW partials: SK @ Wq, K split 4 ways (2048 blocks for occupancy)
    gemm_ab_f32_ksplit<<<dim3(D_DIM / 128, NSLOTS / 128, KSPLIT), blk, 0, stream>>>(
        sk, wq, kwpart, NSLOTS, D_DIM, D_DIM);

    // KW = sum(partials); kwb = bf16(KW)
    reduce_kw<<<dim3((NSLOTS * (size_t)D_DIM) / 1024), blk, 0, stream>>>(
        kwpart, KW, kwb);

    // bf16 copies
    cvt_f32_bf16<<<dim3((BT_DIM * (size_t)D_DIM) / 2048), blk, 0, stream>>>(x, xb);
    cvt_f32_bf16<<<dim3((D_DIM * (size_t)D_DIM) / 2048), blk, 0, stream>>>(wout, woutb);
    cvt_f32_bf16<<<dim3((NSLOTS * (size_t)D_DIM) / 2048), blk, 0, stream>>>(sv, svb);

    // approx scores (bf16 out) = xb @ kwb^T   [overwrites kwpart region]
    gemm_bf16_abt<true><<<dim3(NSLOTS / 128, BT_DIM / 128), blk, 0, stream>>>(
        xb, kwb, scoresb, BT_DIM, NSLOTS, D_DIM);

    // exact top-4 via margin-refine; writes retrieved (bf16) over xb
    topk_refine<<<dim3(BT_DIM / 4), blk, 0, stream>>>(scoresb, x, KW, svb, xb);

    // out = retrieved @ Wout^T  (fp32 out)
    gemm_bf16_abt<false><<<dim3(D_DIM / 128, BT_DIM / 128), blk, 0, stream>>>(
        xb, woutb, (float*)d_out, BT_DIM, D_DIM, D_DIM);
}